// Round 1
// baseline (262.474 us; speedup 1.0000x reference)
//
#include <hip/hip_runtime.h>
#include <hip/hip_bf16.h>

#define BB  8
#define CC  128
#define LXX 4096
#define LYY 1024
#define HH  4
#define DHH 32

typedef __attribute__((ext_vector_type(8))) short bf16x8;
typedef __attribute__((ext_vector_type(4))) float f32x4;

static __device__ __forceinline__ unsigned short f2bf(float f) {
    __hip_bfloat16 h = __float2bfloat16(f);
    return *reinterpret_cast<unsigned short*>(&h);
}

// ---------------- prep: transpose in_proj_w rows 0..255 into wt_q[c][c'], wt_k[c][c'] ----------------
__global__ void prep_kernel(const float* __restrict__ W, float* __restrict__ wtq, float* __restrict__ wtk) {
    int gid = blockIdx.x * 256 + threadIdx.x;   // [0, 32768)
    int row = gid >> 7;                          // 0..255
    int c = gid & 127;
    float v = W[gid];                            // coalesced read
    if (row < CC) wtq[c * CC + row] = v;
    else          wtk[c * CC + (row - CC)] = v;
}

// ---------------- projection: out[b][l][c'] = bf16( (sum_c x[b][c][l] * wt[c][c'] + bias[c']) * scale )
// block 256 threads: 64 l x 128 c' tile. thread: 8 l x 4 c'.
__global__ void proj_kernel(const float* __restrict__ xin, const float* __restrict__ wt,
                            const float* __restrict__ bias, unsigned short* __restrict__ out,
                            int L, float scale) {
    int tid = threadIdx.x;
    int tx = tid & 31, ty = tid >> 5;
    int b = blockIdx.y;
    int l0 = blockIdx.x * 64 + ty * 8;
    int c0 = tx * 4;
    const float* xb = xin + (size_t)b * CC * L + l0;
    float acc[8][4];
#pragma unroll
    for (int j = 0; j < 8; ++j)
#pragma unroll
        for (int r = 0; r < 4; ++r) acc[j][r] = 0.f;

    for (int c = 0; c < CC; ++c) {
        float4 w = *(const float4*)(wt + (size_t)c * CC + c0);
        const float* xp = xb + (size_t)c * L;
        float4 xa = *(const float4*)(xp);
        float4 xc = *(const float4*)(xp + 4);
        float xs[8] = {xa.x, xa.y, xa.z, xa.w, xc.x, xc.y, xc.z, xc.w};
#pragma unroll
        for (int j = 0; j < 8; ++j) {
            acc[j][0] = fmaf(w.x, xs[j], acc[j][0]);
            acc[j][1] = fmaf(w.y, xs[j], acc[j][1]);
            acc[j][2] = fmaf(w.z, xs[j], acc[j][2]);
            acc[j][3] = fmaf(w.w, xs[j], acc[j][3]);
        }
    }
    float4 b4 = *(const float4*)(bias + c0);
#pragma unroll
    for (int j = 0; j < 8; ++j) {
        ushort4 u;
        u.x = f2bf((acc[j][0] + b4.x) * scale);
        u.y = f2bf((acc[j][1] + b4.y) * scale);
        u.z = f2bf((acc[j][2] + b4.z) * scale);
        u.w = f2bf((acc[j][3] + b4.w) * scale);
        *(ushort4*)(out + ((size_t)(b * L + l0 + j)) * CC + c0) = u;
    }
}

// ---------------- local path: sigmoid(conv2 . relu(conv1 . x)) , one thread per (b,l) ----------------
__global__ void conv_kernel(const float* __restrict__ x, const float* __restrict__ w1,
                            const float* __restrict__ b1, const float* __restrict__ w2,
                            const float* __restrict__ b2, float* __restrict__ localS) {
    int b = blockIdx.y;
    int l = blockIdx.x * 256 + threadIdx.x;
    float acc[32];
#pragma unroll
    for (int o = 0; o < 32; ++o) acc[o] = b1[o];
    const float* xb = x + (size_t)b * CC * LXX + l;
    for (int c = 0; c < CC; ++c) {
        float xv = xb[(size_t)c * LXX];             // coalesced across lanes
#pragma unroll
        for (int o = 0; o < 32; ++o) acc[o] = fmaf(w1[o * CC + c], xv, acc[o]);
    }
    float s = b2[0];
#pragma unroll
    for (int o = 0; o < 32; ++o) s += w2[o] * fmaxf(acc[o], 0.0f);
    localS[(size_t)b * LXX + l] = 1.0f / (1.0f + __expf(-s));
}

// ---------------- fused attention: scores (MFMA bf16) + softmax + head-mean + key-max + gating blend
// block = 256 thr (4 waves), per block: 16 q rows, wave w owns keys [w*256, w*256+256).
// scores for one head live in regs: s[16] f32x4 (D layout: key=lane&15, row=quad*4+reg).
__global__ __launch_bounds__(256, 2) void attn_kernel(
    const unsigned short* __restrict__ Qb, const unsigned short* __restrict__ Kb,
    const float* __restrict__ localS,
    const float* __restrict__ gw, const float* __restrict__ gb,
    float* __restrict__ out)
{
    int tid = threadIdx.x;
    int wave = tid >> 6;
    int lane = tid & 63;
    int n16 = lane & 15;
    int quad = lane >> 4;
    int bi = blockIdx.y;
    int q0 = blockIdx.x * 16;

    __shared__ float xred[4][16];
    __shared__ float xsum[4][16];

    const unsigned short* Qp = Qb + ((size_t)bi * LXX + q0 + n16) * CC + quad * 8;
    const unsigned short* Kp = Kb + ((size_t)bi * LYY + wave * 256 + n16) * CC + quad * 8;

    const f32x4 fzero = {0.f, 0.f, 0.f, 0.f};
    f32x4 vAcc[16];
#pragma unroll
    for (int t = 0; t < 16; ++t) vAcc[t] = fzero;

#pragma unroll 1
    for (int h = 0; h < HH; ++h) {
        bf16x8 afr = *(const bf16x8*)(Qp + h * DHH);
        f32x4 s[16];
#pragma unroll
        for (int t = 0; t < 16; ++t) {
            bf16x8 bfr = *(const bf16x8*)(Kp + (size_t)t * 16 * CC + h * DHH);
            s[t] = __builtin_amdgcn_mfma_f32_16x16x32_bf16(afr, bfr, fzero, 0, 0, 0);
        }
        // per-row max: regs -> 16 key-lanes -> cross-wave via LDS
        float mr[4] = {-1e30f, -1e30f, -1e30f, -1e30f};
#pragma unroll
        for (int t = 0; t < 16; ++t)
#pragma unroll
            for (int r = 0; r < 4; ++r) mr[r] = fmaxf(mr[r], s[t][r]);
#pragma unroll
        for (int off = 1; off < 16; off <<= 1)
#pragma unroll
            for (int r = 0; r < 4; ++r) mr[r] = fmaxf(mr[r], __shfl_xor(mr[r], off, 64));
        if (n16 == 0) {
#pragma unroll
            for (int r = 0; r < 4; ++r) xred[wave][quad * 4 + r] = mr[r];
        }
        __syncthreads();
        float m4[4];
#pragma unroll
        for (int r = 0; r < 4; ++r) {
            int row = quad * 4 + r;
            m4[r] = fmaxf(fmaxf(xred[0][row], xred[1][row]), fmaxf(xred[2][row], xred[3][row]));
        }
        // exp + per-row sum
        float lr[4] = {0.f, 0.f, 0.f, 0.f};
#pragma unroll
        for (int t = 0; t < 16; ++t)
#pragma unroll
            for (int r = 0; r < 4; ++r) {
                float e = __expf(s[t][r] - m4[r]);
                s[t][r] = e;
                lr[r] += e;
            }
#pragma unroll
        for (int off = 1; off < 16; off <<= 1)
#pragma unroll
            for (int r = 0; r < 4; ++r) lr[r] += __shfl_xor(lr[r], off, 64);
        if (n16 == 0) {
#pragma unroll
            for (int r = 0; r < 4; ++r) xsum[wave][quad * 4 + r] = lr[r];
        }
        __syncthreads();
#pragma unroll
        for (int r = 0; r < 4; ++r) {
            int row = quad * 4 + r;
            float inv = 1.0f / (xsum[0][row] + xsum[1][row] + xsum[2][row] + xsum[3][row]);
#pragma unroll
            for (int t = 0; t < 16; ++t) vAcc[t][r] += s[t][r] * inv;
        }
    }
    // max over keys of sum-over-heads
    float vm[4] = {-1e30f, -1e30f, -1e30f, -1e30f};
#pragma unroll
    for (int t = 0; t < 16; ++t)
#pragma unroll
        for (int r = 0; r < 4; ++r) vm[r] = fmaxf(vm[r], vAcc[t][r]);
#pragma unroll
    for (int off = 1; off < 16; off <<= 1)
#pragma unroll
        for (int r = 0; r < 4; ++r) vm[r] = fmaxf(vm[r], __shfl_xor(vm[r], off, 64));
    // xred reads for h=3 all happened before the last __syncthreads -> safe to overwrite
    if (n16 == 0) {
#pragma unroll
        for (int r = 0; r < 4; ++r) xred[wave][quad * 4 + r] = vm[r];
    }
    __syncthreads();
    if (tid < 16) {
        int row = tid;
        float cs = 0.25f * fmaxf(fmaxf(xred[0][row], xred[1][row]), fmaxf(xred[2][row], xred[3][row]));
        float ls = localS[(size_t)bi * LXX + q0 + row];
        float z = gw[0] * cs + gw[1] * ls + gb[0];
        float alpha = 1.0f / (1.0f + __expf(-z));
        out[(size_t)bi * LXX + q0 + row] = alpha * cs + (1.0f - alpha) * ls;
    }
}

extern "C" void kernel_launch(void* const* d_in, const int* in_sizes, int n_in,
                              void* d_out, int out_size, void* d_ws, size_t ws_size,
                              hipStream_t stream) {
    const float* x   = (const float*)d_in[0];
    const float* y   = (const float*)d_in[1];
    const float* ipw = (const float*)d_in[2];
    const float* ipb = (const float*)d_in[3];
    const float* c1w = (const float*)d_in[4];
    const float* c1b = (const float*)d_in[5];
    const float* c2w = (const float*)d_in[6];
    const float* c2b = (const float*)d_in[7];
    const float* gw  = (const float*)d_in[8];
    const float* gb  = (const float*)d_in[9];
    float* out = (float*)d_out;

    // workspace carve (~10.3 MB)
    float* wtq   = (float*)d_ws;                         // 16384 f32
    float* wtk   = wtq + 16384;                          // 16384 f32
    float* localS= wtk + 16384;                          // 32768 f32
    unsigned short* Qb = (unsigned short*)(localS + 32768);       // B*LX*C bf16
    unsigned short* Kb = Qb + (size_t)BB * LXX * CC;              // B*LY*C bf16

    const float qscale = 0.17677669529663687f;  // 1/sqrt(32)

    hipLaunchKernelGGL(prep_kernel, dim3(128), dim3(256), 0, stream, ipw, wtq, wtk);
    hipLaunchKernelGGL(proj_kernel, dim3(LXX / 64, BB), dim3(256), 0, stream,
                       x, wtq, ipb, Qb, LXX, qscale);
    hipLaunchKernelGGL(proj_kernel, dim3(LYY / 64, BB), dim3(256), 0, stream,
                       y, wtk, ipb + CC, Kb, LYY, 1.0f);
    hipLaunchKernelGGL(conv_kernel, dim3(LXX / 256, BB), dim3(256), 0, stream,
                       x, c1w, c1b, c2w, c2b, localS);
    hipLaunchKernelGGL(attn_kernel, dim3(LXX / 16, BB), dim3(256), 0, stream,
                       Qb, Kb, localS, gw, gb, out);
}

// Round 2
// 179.157 us; speedup vs baseline: 1.4651x; 1.4651x over previous
//
#include <hip/hip_runtime.h>
#include <hip/hip_bf16.h>

#define BB  8
#define CC  128
#define LXX 4096
#define LYY 1024
#define HH  4
#define DHH 32

typedef __attribute__((ext_vector_type(8))) short bf16x8;
typedef __attribute__((ext_vector_type(4))) float f32x4;

static __device__ __forceinline__ unsigned short f2bf(float f) {
    __hip_bfloat16 h = __float2bfloat16(f);
    return *reinterpret_cast<unsigned short*>(&h);
}

// ---------------- prep: transpose in_proj_w rows 0..255 -> wtq[c][c'], wtk[c][c'];
// transpose conv1_w (32,128) -> w1t[c][o] (128,32)
__global__ void prep_kernel(const float* __restrict__ W, const float* __restrict__ c1w,
                            float* __restrict__ wtq, float* __restrict__ wtk,
                            float* __restrict__ w1t) {
    int gid = blockIdx.x * 256 + threadIdx.x;
    if (gid < 32768) {
        int row = gid >> 7;
        int c = gid & 127;
        float v = W[gid];
        if (row < CC) wtq[c * CC + row] = v;
        else          wtk[c * CC + (row - CC)] = v;
    } else if (gid < 32768 + 4096) {
        int g2 = gid - 32768;
        int o = g2 >> 7;
        int c = g2 & 127;
        w1t[c * 32 + o] = c1w[g2];
    }
}

// ---------------- projection (+ optionally fused conv path for x)
// out[b][h][l][dh] = bf16( (sum_c x[b][c][l] * wt[c][c'] + bias[c']) * scale ),  h=c'>>5, dh=c'&31
// block 256 thr: 32 l x 128 c' tile; thread: 4 l x 4 c'. grid (L/32, B).
template <bool DO_CONV>
__global__ __launch_bounds__(256) void proj_kernel(
    const float* __restrict__ xin, const float* __restrict__ wt,
    const float* __restrict__ bias, unsigned short* __restrict__ outQ,
    const float* __restrict__ w1t, const float* __restrict__ b1,
    const float* __restrict__ w2, const float* __restrict__ b2,
    float* __restrict__ localS, int L, float scale)
{
    int tid = threadIdx.x;
    int tx = tid & 31, ty = tid >> 5;
    int b = blockIdx.y;
    int l0 = blockIdx.x * 32 + ty * 4;
    int c0 = tx * 4;
    const float* xb = xin + (size_t)b * CC * L + l0;

    float acc[4][4];
#pragma unroll
    for (int j = 0; j < 4; ++j)
#pragma unroll
        for (int r = 0; r < 4; ++r) acc[j][r] = 0.f;
    float accc[4] = {0.f, 0.f, 0.f, 0.f};

    for (int c = 0; c < CC; ++c) {
        float4 w = *(const float4*)(wt + (size_t)c * CC + c0);
        float4 x4 = *(const float4*)(xb + (size_t)c * L);
        float xs[4] = {x4.x, x4.y, x4.z, x4.w};
#pragma unroll
        for (int j = 0; j < 4; ++j) {
            acc[j][0] = fmaf(w.x, xs[j], acc[j][0]);
            acc[j][1] = fmaf(w.y, xs[j], acc[j][1]);
            acc[j][2] = fmaf(w.z, xs[j], acc[j][2]);
            acc[j][3] = fmaf(w.w, xs[j], acc[j][3]);
        }
        if (DO_CONV) {
            float wc = w1t[c * 32 + tx];
#pragma unroll
            for (int j = 0; j < 4; ++j) accc[j] = fmaf(wc, xs[j], accc[j]);
        }
    }
    float4 b4 = *(const float4*)(bias + c0);
    int h = c0 >> 5, d = c0 & 31;
#pragma unroll
    for (int j = 0; j < 4; ++j) {
        ushort4 u;
        u.x = f2bf((acc[j][0] + b4.x) * scale);
        u.y = f2bf((acc[j][1] + b4.y) * scale);
        u.z = f2bf((acc[j][2] + b4.z) * scale);
        u.w = f2bf((acc[j][3] + b4.w) * scale);
        *(ushort4*)(outQ + (((size_t)(b * HH + h) * L) + l0 + j) * DHH + d) = u;
    }
    if (DO_CONV) {
        float w2v = w2[tx];
        float b1v = b1[tx];
        float b2v = b2[0];
#pragma unroll
        for (int j = 0; j < 4; ++j) {
            float hv = fmaxf(accc[j] + b1v, 0.0f);
            float p = w2v * hv;
#pragma unroll
            for (int off = 1; off < 32; off <<= 1) p += __shfl_xor(p, off, 64);
            if (tx == 0) {
                float s = p + b2v;
                localS[(size_t)b * L + l0 + j] = 1.0f / (1.0f + __expf(-s));
            }
        }
    }
}

// ---------------- fused attention v2: no-max softmax (exp2 domain), 1 barrier/head
// block = 256 thr (4 waves): 16 q rows, wave w owns keys [w*256, +256).
// Q/K head-major: [b][h][l][32] -> every MFMA fragment load is 1KB contiguous.
__global__ __launch_bounds__(256, 3) void attn_kernel(
    const unsigned short* __restrict__ Qh, const unsigned short* __restrict__ Kh,
    const float* __restrict__ localS,
    const float* __restrict__ gw, const float* __restrict__ gb,
    float* __restrict__ out)
{
    int tid = threadIdx.x;
    int wave = tid >> 6;
    int lane = tid & 63;
    int n16 = lane & 15;
    int quad = lane >> 4;
    int bi = blockIdx.y;
    int q0 = blockIdx.x * 16;
    int row = quad * 4;   // base row this lane holds (rows row..row+3 in regs r)

    __shared__ float lbuf[HH][4][16];
    __shared__ float mbuf[4][16];

    const unsigned short* Qp = Qh + (((size_t)bi * HH) * LXX + q0 + n16) * DHH + quad * 8;
    const unsigned short* Kp = Kh + (((size_t)bi * HH) * LYY + wave * 256 + n16) * DHH + quad * 8;

    const f32x4 fzero = {0.f, 0.f, 0.f, 0.f};
    f32x4 vAcc[16];
#pragma unroll
    for (int t = 0; t < 16; ++t) vAcc[t] = fzero;

#pragma unroll 1
    for (int h = 0; h < HH; ++h) {
        bf16x8 afr = *(const bf16x8*)(Qp + (size_t)h * LXX * DHH);
        const unsigned short* Kph = Kp + (size_t)h * LYY * DHH;
        f32x4 s[16];
#pragma unroll
        for (int t = 0; t < 16; ++t) {
            bf16x8 bfr = *(const bf16x8*)(Kph + (size_t)t * 16 * DHH);
            s[t] = __builtin_amdgcn_mfma_f32_16x16x32_bf16(afr, bfr, fzero, 0, 0, 0);
        }
        // exp2 (log2e folded into Q scale) + per-row sum; no max pass (|s| << 120, safe)
        float lr[4] = {0.f, 0.f, 0.f, 0.f};
#pragma unroll
        for (int t = 0; t < 16; ++t)
#pragma unroll
            for (int r = 0; r < 4; ++r) {
                float e = __builtin_amdgcn_exp2f(s[t][r]);
                s[t][r] = e;
                lr[r] += e;
            }
#pragma unroll
        for (int off = 1; off < 16; off <<= 1)
#pragma unroll
            for (int r = 0; r < 4; ++r) lr[r] += __shfl_xor(lr[r], off, 64);
        if (n16 == 0) {
#pragma unroll
            for (int r = 0; r < 4; ++r) lbuf[h][wave][row + r] = lr[r];
        }
        __syncthreads();
#pragma unroll
        for (int r = 0; r < 4; ++r) {
            float inv = 1.0f / (lbuf[h][0][row + r] + lbuf[h][1][row + r] +
                                lbuf[h][2][row + r] + lbuf[h][3][row + r]);
#pragma unroll
            for (int t = 0; t < 16; ++t) vAcc[t][r] += s[t][r] * inv;
        }
        // next head writes lbuf[h+1] (different slots) -> no extra barrier needed
    }
    // max over this wave's 256 keys of the head-sum
    float vm[4] = {-1e30f, -1e30f, -1e30f, -1e30f};
#pragma unroll
    for (int t = 0; t < 16; ++t)
#pragma unroll
        for (int r = 0; r < 4; ++r) vm[r] = fmaxf(vm[r], vAcc[t][r]);
#pragma unroll
    for (int off = 1; off < 16; off <<= 1)
#pragma unroll
        for (int r = 0; r < 4; ++r) vm[r] = fmaxf(vm[r], __shfl_xor(vm[r], off, 64));
    if (n16 == 0) {
#pragma unroll
        for (int r = 0; r < 4; ++r) mbuf[wave][row + r] = vm[r];
    }
    __syncthreads();
    if (tid < 16) {
        float cs = 0.25f * fmaxf(fmaxf(mbuf[0][tid], mbuf[1][tid]), fmaxf(mbuf[2][tid], mbuf[3][tid]));
        float ls = localS[(size_t)bi * LXX + q0 + tid];
        float z = gw[0] * cs + gw[1] * ls + gb[0];
        float alpha = 1.0f / (1.0f + __expf(-z));
        out[(size_t)bi * LXX + q0 + tid] = alpha * cs + (1.0f - alpha) * ls;
    }
}

extern "C" void kernel_launch(void* const* d_in, const int* in_sizes, int n_in,
                              void* d_out, int out_size, void* d_ws, size_t ws_size,
                              hipStream_t stream) {
    const float* x   = (const float*)d_in[0];
    const float* y   = (const float*)d_in[1];
    const float* ipw = (const float*)d_in[2];
    const float* ipb = (const float*)d_in[3];
    const float* c1w = (const float*)d_in[4];
    const float* c1b = (const float*)d_in[5];
    const float* c2w = (const float*)d_in[6];
    const float* c2b = (const float*)d_in[7];
    const float* gw  = (const float*)d_in[8];
    const float* gb  = (const float*)d_in[9];
    float* out = (float*)d_out;

    // workspace carve (~10.8 MB)
    float* wtq    = (float*)d_ws;                        // 16384 f32
    float* wtk    = wtq + 16384;                         // 16384 f32
    float* w1t    = wtk + 16384;                         // 4096  f32
    float* localS = w1t + 4096;                          // 32768 f32
    unsigned short* Qb = (unsigned short*)(localS + 32768);   // B*H*LX*DH bf16
    unsigned short* Kb = Qb + (size_t)BB * HH * LXX * DHH;    // B*H*LY*DH bf16

    // 1/sqrt(32) * log2(e): exp2-domain softmax
    const float qscale = 0.17677669529663687f * 1.4426950408889634f;

    hipLaunchKernelGGL(prep_kernel, dim3(144), dim3(256), 0, stream, ipw, c1w, wtq, wtk, w1t);
    hipLaunchKernelGGL((proj_kernel<true>), dim3(LXX / 32, BB), dim3(256), 0, stream,
                       x, wtq, ipb, Qb, w1t, c1b, c2w, c2b, localS, LXX, qscale);
    hipLaunchKernelGGL((proj_kernel<false>), dim3(LYY / 32, BB), dim3(256), 0, stream,
                       y, wtk, ipb + CC, Kb, nullptr, nullptr, nullptr, nullptr, nullptr, LYY, 1.0f);
    hipLaunchKernelGGL(attn_kernel, dim3(LXX / 16, BB), dim3(256), 0, stream,
                       Qb, Kb, localS, gw, gb, out);
}

// Round 3
// 154.078 us; speedup vs baseline: 1.7035x; 1.1628x over previous
//
#include <hip/hip_runtime.h>
#include <hip/hip_bf16.h>

#define BB  8
#define CC  128
#define LXX 4096
#define LYY 1024
#define HH  4
#define DHH 32

typedef __attribute__((ext_vector_type(8))) short bf16x8;
typedef __attribute__((ext_vector_type(4))) float f32x4;

static __device__ __forceinline__ unsigned short f2bf(float f) {
    __hip_bfloat16 h = __float2bfloat16(f);
    return *reinterpret_cast<unsigned short*>(&h);
}

static __device__ __forceinline__ bf16x8 pack8(const float* f) {
    bf16x8 r;
#pragma unroll
    for (int i = 0; i < 8; ++i) {
        __hip_bfloat16 h = __float2bfloat16(f[i]);
        r[i] = *reinterpret_cast<short*>(&h);
    }
    return r;
}

// ================= merged MFMA projection (+fused conv for x) =================
// D[m=c'][n=l] = sum_c W[c'][c] * src[c][l]   (A = W row-major, B = src strided)
// block 256 thr = 4 waves; wave handles 16 l  x  all 128 c'.
// grid: blocks [0,512) = x-branch (b = blk>>6, l0 = (blk&63)*64),
//       blocks [512,640) = y-branch (b = (blk-512)>>4, l0 = ((blk-512)&15)*64).
__global__ __launch_bounds__(256) void proj_all_kernel(
    const float* __restrict__ x, const float* __restrict__ y,
    const float* __restrict__ ipw, const float* __restrict__ ipb,
    const float* __restrict__ c1w, const float* __restrict__ c1b,
    const float* __restrict__ c2w, const float* __restrict__ c2b,
    unsigned short* __restrict__ Qb, unsigned short* __restrict__ Kb,
    float* __restrict__ localS, float qscale)
{
    int tid  = threadIdx.x;
    int wv   = tid >> 6;
    int lane = tid & 63;
    int n16  = lane & 15;
    int quad = lane >> 4;

    int blk = blockIdx.x;
    bool isX = (blk < 512);
    const float* src; const float* wrow; const float* bias;
    unsigned short* dst; int L, bi, l0; float scale;
    if (isX) {
        bi = blk >> 6; l0 = (blk & 63) * 64;
        src = x + (size_t)bi * CC * LXX; L = LXX;
        wrow = ipw; bias = ipb; dst = Qb; scale = qscale;
    } else {
        int b2 = blk - 512;
        bi = b2 >> 4; l0 = (b2 & 15) * 64;
        src = y + (size_t)bi * CC * LYY; L = LYY;
        wrow = ipw + CC * CC; bias = ipb + CC; dst = Kb; scale = 1.0f;
    }
    int lw = l0 + wv * 16;          // this wave's 16-l tile base
    int myl = lw + n16;             // lane's l (as B-frag n index)

    // ---- B-fragments: x[c][l] for k = kk*32 + quad*8 + j ----
    bf16x8 bfr[4];
#pragma unroll
    for (int kk = 0; kk < 4; ++kk) {
        float t[8];
        const float* p = src + (size_t)(kk * 32 + quad * 8) * L + myl;
#pragma unroll
        for (int j = 0; j < 8; ++j) t[j] = p[(size_t)j * L];
        bfr[kk] = pack8(t);
    }

    const f32x4 fzero = {0.f, 0.f, 0.f, 0.f};

    // ---- Q/K projection: 8 m-tiles of 16 c' ----
#pragma unroll 1
    for (int m = 0; m < 8; ++m) {
        int mc = m * 16;
        f32x4 acc = fzero;
#pragma unroll
        for (int kk = 0; kk < 4; ++kk) {
            const float* wp = wrow + (size_t)(mc + n16) * CC + kk * 32 + quad * 8;
            float t[8];
            *(float4*)(t) = *(const float4*)(wp);
            *(float4*)(t + 4) = *(const float4*)(wp + 4);
            bf16x8 afr = pack8(t);
            acc = __builtin_amdgcn_mfma_f32_16x16x32_bf16(afr, bfr[kk], acc, 0, 0, 0);
        }
        // D: row = quad*4+r = c'-local, col = n16 = l-local
        int h = mc >> 5, d0 = (mc & 31) + quad * 4;
        ushort4 u;
        float4 bq = *(const float4*)(bias + mc + quad * 4);
        u.x = f2bf((acc[0] + bq.x) * scale);
        u.y = f2bf((acc[1] + bq.y) * scale);
        u.z = f2bf((acc[2] + bq.z) * scale);
        u.w = f2bf((acc[3] + bq.w) * scale);
        *(ushort4*)(dst + (((size_t)(bi * HH + h) * L) + myl) * DHH + d0) = u;
    }

    // ---- fused conv path (x only): h = relu(conv1.x+b1), ls = sigmoid(conv2.h+b2) ----
    if (isX) {
        float p = 0.f;
#pragma unroll
        for (int m2 = 0; m2 < 2; ++m2) {
            f32x4 hacc = fzero;
#pragma unroll
            for (int kk = 0; kk < 4; ++kk) {
                const float* wp = c1w + (size_t)(m2 * 16 + n16) * CC + kk * 32 + quad * 8;
                float t[8];
                *(float4*)(t) = *(const float4*)(wp);
                *(float4*)(t + 4) = *(const float4*)(wp + 4);
                bf16x8 afr = pack8(t);
                hacc = __builtin_amdgcn_mfma_f32_16x16x32_bf16(afr, bfr[kk], hacc, 0, 0, 0);
            }
#pragma unroll
            for (int r = 0; r < 4; ++r) {
                int o = m2 * 16 + quad * 4 + r;
                p = fmaf(c2w[o], fmaxf(hacc[r] + c1b[o], 0.0f), p);
            }
        }
        // sum over quads (o-groups): lanes sharing n16
        p += __shfl_xor(p, 16, 64);
        p += __shfl_xor(p, 32, 64);
        if (quad == 0) {
            float s = p + c2b[0];
            localS[(size_t)bi * LXX + myl] = 1.0f / (1.0f + __expf(-s));
        }
    }
}

// ================= fused attention (unchanged from round 2) =================
__global__ __launch_bounds__(256, 3) void attn_kernel(
    const unsigned short* __restrict__ Qh, const unsigned short* __restrict__ Kh,
    const float* __restrict__ localS,
    const float* __restrict__ gw, const float* __restrict__ gb,
    float* __restrict__ out)
{
    int tid = threadIdx.x;
    int wave = tid >> 6;
    int lane = tid & 63;
    int n16 = lane & 15;
    int quad = lane >> 4;
    int bi = blockIdx.y;
    int q0 = blockIdx.x * 16;
    int row = quad * 4;

    __shared__ float lbuf[HH][4][16];
    __shared__ float mbuf[4][16];

    const unsigned short* Qp = Qh + (((size_t)bi * HH) * LXX + q0 + n16) * DHH + quad * 8;
    const unsigned short* Kp = Kh + (((size_t)bi * HH) * LYY + wave * 256 + n16) * DHH + quad * 8;

    const f32x4 fzero = {0.f, 0.f, 0.f, 0.f};
    f32x4 vAcc[16];
#pragma unroll
    for (int t = 0; t < 16; ++t) vAcc[t] = fzero;

#pragma unroll 1
    for (int h = 0; h < HH; ++h) {
        bf16x8 afr = *(const bf16x8*)(Qp + (size_t)h * LXX * DHH);
        const unsigned short* Kph = Kp + (size_t)h * LYY * DHH;
        f32x4 s[16];
#pragma unroll
        for (int t = 0; t < 16; ++t) {
            bf16x8 bfr = *(const bf16x8*)(Kph + (size_t)t * 16 * DHH);
            s[t] = __builtin_amdgcn_mfma_f32_16x16x32_bf16(afr, bfr, fzero, 0, 0, 0);
        }
        float lr[4] = {0.f, 0.f, 0.f, 0.f};
#pragma unroll
        for (int t = 0; t < 16; ++t)
#pragma unroll
            for (int r = 0; r < 4; ++r) {
                float e = __builtin_amdgcn_exp2f(s[t][r]);
                s[t][r] = e;
                lr[r] += e;
            }
#pragma unroll
        for (int off = 1; off < 16; off <<= 1)
#pragma unroll
            for (int r = 0; r < 4; ++r) lr[r] += __shfl_xor(lr[r], off, 64);
        if (n16 == 0) {
#pragma unroll
            for (int r = 0; r < 4; ++r) lbuf[h][wave][row + r] = lr[r];
        }
        __syncthreads();
#pragma unroll
        for (int r = 0; r < 4; ++r) {
            float inv = 1.0f / (lbuf[h][0][row + r] + lbuf[h][1][row + r] +
                                lbuf[h][2][row + r] + lbuf[h][3][row + r]);
#pragma unroll
            for (int t = 0; t < 16; ++t) vAcc[t][r] += s[t][r] * inv;
        }
    }
    float vm[4] = {-1e30f, -1e30f, -1e30f, -1e30f};
#pragma unroll
    for (int t = 0; t < 16; ++t)
#pragma unroll
        for (int r = 0; r < 4; ++r) vm[r] = fmaxf(vm[r], vAcc[t][r]);
#pragma unroll
    for (int off = 1; off < 16; off <<= 1)
#pragma unroll
        for (int r = 0; r < 4; ++r) vm[r] = fmaxf(vm[r], __shfl_xor(vm[r], off, 64));
    if (n16 == 0) {
#pragma unroll
        for (int r = 0; r < 4; ++r) mbuf[wave][row + r] = vm[r];
    }
    __syncthreads();
    if (tid < 16) {
        float cs = 0.25f * fmaxf(fmaxf(mbuf[0][tid], mbuf[1][tid]), fmaxf(mbuf[2][tid], mbuf[3][tid]));
        float ls = localS[(size_t)bi * LXX + q0 + tid];
        float z = gw[0] * cs + gw[1] * ls + gb[0];
        float alpha = 1.0f / (1.0f + __expf(-z));
        out[(size_t)bi * LXX + q0 + tid] = alpha * cs + (1.0f - alpha) * ls;
    }
}

extern "C" void kernel_launch(void* const* d_in, const int* in_sizes, int n_in,
                              void* d_out, int out_size, void* d_ws, size_t ws_size,
                              hipStream_t stream) {
    const float* x   = (const float*)d_in[0];
    const float* y   = (const float*)d_in[1];
    const float* ipw = (const float*)d_in[2];
    const float* ipb = (const float*)d_in[3];
    const float* c1w = (const float*)d_in[4];
    const float* c1b = (const float*)d_in[5];
    const float* c2w = (const float*)d_in[6];
    const float* c2b = (const float*)d_in[7];
    const float* gw  = (const float*)d_in[8];
    const float* gb  = (const float*)d_in[9];
    float* out = (float*)d_out;

    float* localS = (float*)d_ws;                                // 32768 f32
    unsigned short* Qb = (unsigned short*)(localS + 32768);      // B*H*LX*DH bf16
    unsigned short* Kb = Qb + (size_t)BB * HH * LXX * DHH;       // B*H*LY*DH bf16

    // 1/sqrt(32) * log2(e): exp2-domain softmax, folded into Q only
    const float qscale = 0.17677669529663687f * 1.4426950408889634f;

    hipLaunchKernelGGL(proj_all_kernel, dim3(640), dim3(256), 0, stream,
                       x, y, ipw, ipb, c1w, c1b, c2w, c2b, Qb, Kb, localS, qscale);
    hipLaunchKernelGGL(attn_kernel, dim3(LXX / 16, BB), dim3(256), 0, stream,
                       Qb, Kb, localS, gw, gb, out);
}